// Round 3
// baseline (190.633 us; speedup 1.0000x reference)
//
#include <hip/hip_runtime.h>
#include <stdint.h>

#define NTOK 4096
#define HDIM 1024
#define DDIM 2048
#define NEXP 8
#define NASS 8192   // NTOK * K (K=2)
#define MAXT 72     // worst-case sum_e ceil(cnt_e/128) = 64 + 7

typedef __attribute__((ext_vector_type(8))) short bf16x8;
typedef __attribute__((ext_vector_type(4))) float f32x4;

typedef __attribute__((address_space(1))) const unsigned int gu32;
typedef __attribute__((address_space(3))) unsigned int lu32;

__device__ __forceinline__ void async16(void* lds, const void* g) {
  __builtin_amdgcn_global_load_lds((gu32*)(uintptr_t)g, (lu32*)(uintptr_t)lds, 16, 0, 0);
}

__device__ __forceinline__ unsigned short f2bf(float f) {
  unsigned int u = __float_as_uint(f);
  return (unsigned short)((u + 0x7fffu + ((u >> 16) & 1u)) >> 16);
}
__device__ __forceinline__ float bf2f(unsigned short u) {
  return __uint_as_float(((unsigned int)u) << 16);
}

// ---------------- x fp32 -> bf16 ----------------
__global__ __launch_bounds__(256) void k_cvt_x(const float* __restrict__ x,
                                               unsigned short* __restrict__ x16) {
  int i = blockIdx.x * 256 + threadIdx.x;
  float4 v = reinterpret_cast<const float4*>(x)[i];
  ushort4 o;
  o.x = f2bf(v.x); o.y = f2bf(v.y); o.z = f2bf(v.z); o.w = f2bf(v.w);
  reinterpret_cast<ushort4*>(x16)[i] = o;
}

// ---------------- [E][R][C] fp32 -> [E][C][R] bf16 (tiled transpose) ----------------
__global__ __launch_bounds__(256) void k_transpose(const float* __restrict__ in,
                                                   unsigned short* __restrict__ out,
                                                   int R, int C) {
  __shared__ float t[32][33];
  const size_t mbase = (size_t)blockIdx.z * R * C;
  int tid = threadIdx.x;
  int r = tid >> 3, c4 = (tid & 7) * 4;
  int gr = blockIdx.y * 32 + r;
  int gc = blockIdx.x * 32 + c4;
  float4 v = *reinterpret_cast<const float4*>(in + mbase + (size_t)gr * C + gc);
  t[r][c4 + 0] = v.x; t[r][c4 + 1] = v.y; t[r][c4 + 2] = v.z; t[r][c4 + 3] = v.w;
  __syncthreads();
  int orow = blockIdx.x * 32 + r;    // original col
  int oc4  = blockIdx.y * 32 + c4;   // original row
  ushort4 o;
  o.x = f2bf(t[c4 + 0][r]); o.y = f2bf(t[c4 + 1][r]);
  o.z = f2bf(t[c4 + 2][r]); o.w = f2bf(t[c4 + 3][r]);
  *reinterpret_cast<ushort4*>(out + mbase + (size_t)orow * R + oc4) = o;
}

// ---------------- routing: detect+count+scan+scatter+tilemap in ONE block ----------------
__global__ __launch_bounds__(1024) void k_route(
    const int* __restrict__ idx, const float* __restrict__ ew,
    const int* __restrict__ amask,
    int* __restrict__ counts_g, int* __restrict__ offs_g,
    int* __restrict__ toks, float* __restrict__ wl, int* __restrict__ slotmap,
    int* __restrict__ tiles_g, int* __restrict__ ntiles_g) {
  __shared__ int cnt[NEXP], cur[NEXP], flag;
  const int t = threadIdx.x;
  if (t < NEXP) cnt[t] = 0;
  if (t == 0) flag = 0;
  __syncthreads();
  // dtype detect: if int64, all high (odd) words are 0
  int lf = 0;
#pragma unroll
  for (int j = 0; j < 4; ++j) {
    int i = t + j * 1024;
    if (idx[2 * i + 1] != 0) lf = 1;
  }
  if (lf) atomicOr(&flag, 1);
  __syncthreads();
  const int is32 = flag;
  int e[8];
#pragma unroll
  for (int j = 0; j < 8; ++j) {
    int i = t + j * 1024;
    int ei = is32 ? idx[i] : idx[2 * i];
    e[j] = ei;
    atomicAdd(&cnt[ei], 1);
  }
  __syncthreads();
  if (t == 0) {
    int off = 0, nt_ = 0;
    for (int k = 0; k < NEXP; ++k) {
      cur[k] = off; offs_g[k] = off; counts_g[k] = cnt[k]; off += cnt[k];
      int m = (cnt[k] + 127) >> 7;
      for (int j = 0; j < m; ++j) tiles_g[nt_++] = (k << 16) | j;
    }
    *ntiles_g = nt_;
  }
  __syncthreads();
#pragma unroll
  for (int j = 0; j < 8; ++j) {
    int i = t + j * 1024;
    int n = i >> 1;
    int slot = atomicAdd(&cur[e[j]], 1);
    toks[slot] = n;
    wl[slot] = ew[i] * (amask[n] ? 1.0f : 0.0f);
    slotmap[i] = slot;
  }
}

// ---------------- grouped GEMM1: hid = relu(X[gather] @ down), m97 structure ----------------
// A: gathered x16 rows [cnt][1024]; B: dnT [e][2048][1024] (k contig). BK=64.
__global__ __launch_bounds__(256) void k_gemm_down(
    const unsigned short* __restrict__ x16, const unsigned short* __restrict__ bT,
    const int* __restrict__ counts, const int* __restrict__ offs,
    const int* __restrict__ toks, unsigned short* __restrict__ hid,
    const int* __restrict__ tiles, const int* __restrict__ ntiles) {
  const int ti = blockIdx.y;
  if (ti >= *ntiles) return;
  const int pk = tiles[ti];
  const int e = pk >> 16;
  const int mt = pk & 0xffff;
  const int cnt = counts[e];
  const int nt = blockIdx.x;
  const int base = offs[e];
  __shared__ alignas(16) char lds[32768];
  char* lA = lds;
  char* lB = lds + 16384;
  const int tid = threadIdx.x;
  const int lane = tid & 63;
  const int wave = tid >> 6;
  const int wrow = (tid >> 7) * 64;
  const int wcol = ((tid >> 6) & 1) * 64;

  // staging: rows of 64 bf16 (128B). LDS linear; global source pre-swizzled so that
  // LDS[row][c] = G[row][c ^ ((row&7)<<4)]  (rule #21)
  const char* gA[4]; const char* gB[4]; char* sA[4]; char* sB[4];
  {
    const int swcol = ((lane & 7) << 4) ^ ((lane >> 3) << 4);
#pragma unroll
    for (int it = 0; it < 4; ++it) {
      int row = wave * 32 + it * 8 + (lane >> 3);
      int sl = mt * 128 + row; if (sl >= cnt) sl = cnt - 1;
      gA[it] = (const char*)(x16 + (size_t)toks[base + sl] * HDIM) + swcol;
      gB[it] = (const char*)(bT + (size_t)e * DDIM * HDIM + (size_t)(nt * 128 + row) * HDIM) + swcol;
      sA[it] = lA + wave * 4096 + it * 1024 + lane * 16;
      sB[it] = lB + wave * 4096 + it * 1024 + lane * 16;
    }
  }
  const int swz = (lane & 7) << 4;
  const int lo = ((lane >> 4) << 4);
  int rowA[4], rowB[4];
#pragma unroll
  for (int m = 0; m < 4; ++m) {
    rowA[m] = (wrow + m * 16 + (lane & 15)) * 128;
    rowB[m] = (wcol + m * 16 + (lane & 15)) * 128;
  }

  f32x4 acc[4][4] = {};
  for (int kk = 0; kk < HDIM; kk += 64) {
#pragma unroll
    for (int it = 0; it < 4; ++it) {
      async16(sA[it], gA[it] + kk * 2);
      async16(sB[it], gB[it] + kk * 2);
    }
    __syncthreads();
#pragma unroll
    for (int ks = 0; ks < 2; ++ks) {
      const int cx = ((ks << 6) | lo) ^ swz;
      bf16x8 fa[4], fb[4];
#pragma unroll
      for (int m = 0; m < 4; ++m) fa[m] = *reinterpret_cast<const bf16x8*>(lA + rowA[m] + cx);
#pragma unroll
      for (int n = 0; n < 4; ++n) fb[n] = *reinterpret_cast<const bf16x8*>(lB + rowB[n] + cx);
#pragma unroll
      for (int m = 0; m < 4; ++m)
#pragma unroll
        for (int n = 0; n < 4; ++n)
          acc[m][n] = __builtin_amdgcn_mfma_f32_16x16x32_bf16(fa[m], fb[n], acc[m][n], 0, 0, 0);
    }
    __syncthreads();
  }

#pragma unroll
  for (int m = 0; m < 4; ++m) {
    int r0 = mt * 128 + wrow + m * 16 + ((lane >> 4) * 4);
#pragma unroll
    for (int j = 0; j < 4; ++j) {
      int r = r0 + j;
      if (r < cnt) {
        unsigned short* dst = hid + (size_t)(base + r) * DDIM + nt * 128 + wcol + (lane & 15);
#pragma unroll
        for (int n = 0; n < 4; ++n) {
          float v = acc[m][n][j];
          dst[n * 16] = f2bf(v > 0.f ? v : 0.f);
        }
      }
    }
  }
}

// ---------------- grouped GEMM2 (K-split 2): yw[ksp][slot] = partial(hid @ up) ----------------
__global__ __launch_bounds__(256) void k_gemm_up(
    const unsigned short* __restrict__ hid, const unsigned short* __restrict__ bT,
    const int* __restrict__ counts, const int* __restrict__ offs,
    unsigned short* __restrict__ yw,
    const int* __restrict__ tiles, const int* __restrict__ ntiles) {
  const int ti = blockIdx.y;
  if (ti >= *ntiles) return;
  const int pk = tiles[ti];
  const int e = pk >> 16;
  const int mt = pk & 0xffff;
  const int cnt = counts[e];
  const int ksp = blockIdx.x >> 3;
  const int nt = blockIdx.x & 7;
  const int base = offs[e];
  __shared__ alignas(16) char lds[32768];
  char* lA = lds;
  char* lB = lds + 16384;
  const int tid = threadIdx.x;
  const int lane = tid & 63;
  const int wave = tid >> 6;
  const int wrow = (tid >> 7) * 64;
  const int wcol = ((tid >> 6) & 1) * 64;

  const char* gA[4]; const char* gB[4]; char* sA[4]; char* sB[4];
  {
    const int swcol = ((lane & 7) << 4) ^ ((lane >> 3) << 4);
#pragma unroll
    for (int it = 0; it < 4; ++it) {
      int row = wave * 32 + it * 8 + (lane >> 3);
      int sl = mt * 128 + row; if (sl >= cnt) sl = cnt - 1;
      gA[it] = (const char*)(hid + (size_t)(base + sl) * DDIM + ksp * 1024) + swcol;
      gB[it] = (const char*)(bT + (size_t)e * HDIM * DDIM + (size_t)(nt * 128 + row) * DDIM + ksp * 1024) + swcol;
      sA[it] = lA + wave * 4096 + it * 1024 + lane * 16;
      sB[it] = lB + wave * 4096 + it * 1024 + lane * 16;
    }
  }
  const int swz = (lane & 7) << 4;
  const int lo = ((lane >> 4) << 4);
  int rowA[4], rowB[4];
#pragma unroll
  for (int m = 0; m < 4; ++m) {
    rowA[m] = (wrow + m * 16 + (lane & 15)) * 128;
    rowB[m] = (wcol + m * 16 + (lane & 15)) * 128;
  }

  f32x4 acc[4][4] = {};
  for (int kk = 0; kk < 1024; kk += 64) {
#pragma unroll
    for (int it = 0; it < 4; ++it) {
      async16(sA[it], gA[it] + kk * 2);
      async16(sB[it], gB[it] + kk * 2);
    }
    __syncthreads();
#pragma unroll
    for (int ks = 0; ks < 2; ++ks) {
      const int cx = ((ks << 6) | lo) ^ swz;
      bf16x8 fa[4], fb[4];
#pragma unroll
      for (int m = 0; m < 4; ++m) fa[m] = *reinterpret_cast<const bf16x8*>(lA + rowA[m] + cx);
#pragma unroll
      for (int n = 0; n < 4; ++n) fb[n] = *reinterpret_cast<const bf16x8*>(lB + rowB[n] + cx);
#pragma unroll
      for (int m = 0; m < 4; ++m)
#pragma unroll
        for (int n = 0; n < 4; ++n)
          acc[m][n] = __builtin_amdgcn_mfma_f32_16x16x32_bf16(fa[m], fb[n], acc[m][n], 0, 0, 0);
    }
    __syncthreads();
  }

#pragma unroll
  for (int m = 0; m < 4; ++m) {
    int r0 = mt * 128 + wrow + m * 16 + ((lane >> 4) * 4);
#pragma unroll
    for (int j = 0; j < 4; ++j) {
      int r = r0 + j;
      if (r < cnt) {
        unsigned short* dst = yw + ((size_t)ksp * NASS + base + r) * HDIM
                              + nt * 128 + wcol + (lane & 15);
#pragma unroll
        for (int n = 0; n < 4; ++n) dst[n * 16] = f2bf(acc[m][n][j]);
      }
    }
  }
}

// ---------------- combine: out = x + w0*(p00+p01) + w1*(p10+p11) ----------------
__global__ __launch_bounds__(256) void k_combine(
    const float* __restrict__ x, const unsigned short* __restrict__ yw,
    const int* __restrict__ slotmap, const float* __restrict__ wl,
    float* __restrict__ out) {
  const int n = blockIdx.x;
  const int t = threadIdx.x;
  const int s0 = slotmap[2 * n], s1 = slotmap[2 * n + 1];
  const float w0 = wl[s0], w1 = wl[s1];
  float4 xv = reinterpret_cast<const float4*>(x + (size_t)n * HDIM)[t];
  ushort4 a0 = reinterpret_cast<const ushort4*>(yw + (size_t)s0 * HDIM)[t];
  ushort4 a1 = reinterpret_cast<const ushort4*>(yw + ((size_t)NASS + s0) * HDIM)[t];
  ushort4 b0 = reinterpret_cast<const ushort4*>(yw + (size_t)s1 * HDIM)[t];
  ushort4 b1 = reinterpret_cast<const ushort4*>(yw + ((size_t)NASS + s1) * HDIM)[t];
  float4 r;
  r.x = xv.x + w0 * (bf2f(a0.x) + bf2f(a1.x)) + w1 * (bf2f(b0.x) + bf2f(b1.x));
  r.y = xv.y + w0 * (bf2f(a0.y) + bf2f(a1.y)) + w1 * (bf2f(b0.y) + bf2f(b1.y));
  r.z = xv.z + w0 * (bf2f(a0.z) + bf2f(a1.z)) + w1 * (bf2f(b0.z) + bf2f(b1.z));
  r.w = xv.w + w0 * (bf2f(a0.w) + bf2f(a1.w)) + w1 * (bf2f(b0.w) + bf2f(b1.w));
  reinterpret_cast<float4*>(out + (size_t)n * HDIM)[t] = r;
}

extern "C" void kernel_launch(void* const* d_in, const int* in_sizes, int n_in,
                              void* d_out, int out_size, void* d_ws, size_t ws_size,
                              hipStream_t stream) {
  const float* x    = (const float*)d_in[0];
  const int* amask  = (const int*)d_in[1];
  const float* ew   = (const float*)d_in[2];
  const int* cidx   = (const int*)d_in[3];
  const float* dn   = (const float*)d_in[4];
  const float* up   = (const float*)d_in[5];
  float* out        = (float*)d_out;
  char* ws          = (char*)d_ws;

  const size_t X16_OFF = 0;
  const size_t DNT_OFF = X16_OFF + (size_t)NTOK * HDIM * 2;             // 8.4MB
  const size_t UPT_OFF = DNT_OFF + (size_t)NEXP * HDIM * DDIM * 2;      // +33.5MB
  const size_t HID_OFF = UPT_OFF + (size_t)NEXP * HDIM * DDIM * 2;      // +33.5MB
  const size_t MET_OFF = HID_OFF + (size_t)NASS * DDIM * 2;             // +33.5MB

  unsigned short* x16 = (unsigned short*)(ws + X16_OFF);
  unsigned short* dnT = (unsigned short*)(ws + DNT_OFF);
  unsigned short* upT = (unsigned short*)(ws + UPT_OFF);
  unsigned short* hid = (unsigned short*)(ws + HID_OFF);
  // yw ([2][NASS][HDIM] bf16, 33.5MB) aliases dnT: dnT dead after k_gemm_down
  unsigned short* yw  = (unsigned short*)(ws + DNT_OFF);
  int* counts  = (int*)(ws + MET_OFF);
  int* offs    = counts + 8;
  int* toks    = counts + 32;
  float* wl    = (float*)(toks + NASS);
  int* slotmap = (int*)(wl + NASS);
  int* tiles   = slotmap + NASS;
  int* ntiles  = tiles + 128;

  k_cvt_x<<<NTOK * HDIM / 1024, 256, 0, stream>>>(x, x16);
  k_transpose<<<dim3(DDIM / 32, HDIM / 32, NEXP), 256, 0, stream>>>(dn, dnT, HDIM, DDIM);
  k_transpose<<<dim3(HDIM / 32, DDIM / 32, NEXP), 256, 0, stream>>>(up, upT, DDIM, HDIM);
  k_route<<<1, 1024, 0, stream>>>(cidx, ew, amask, counts, offs, toks, wl, slotmap,
                                  tiles, ntiles);
  k_gemm_down<<<dim3(16, MAXT), 256, 0, stream>>>(x16, dnT, counts, offs, toks, hid,
                                                  tiles, ntiles);
  k_gemm_up<<<dim3(16, MAXT), 256, 0, stream>>>(hid, upT, counts, offs, yw,
                                                tiles, ntiles);
  k_combine<<<NTOK, 256, 0, stream>>>(x, yw, slotmap, wl, out);
}

// Round 4
// 177.381 us; speedup vs baseline: 1.0747x; 1.0747x over previous
//
#include <hip/hip_runtime.h>
#include <stdint.h>

#define NTOK 4096
#define HDIM 1024
#define DDIM 2048
#define NEXP 8
#define NASS 8192   // NTOK * K (K=2)
#define MAXT 72     // worst-case sum_e ceil(cnt_e/128) = 64 + 7

typedef __attribute__((ext_vector_type(8))) short bf16x8;
typedef __attribute__((ext_vector_type(4))) float f32x4;

typedef __attribute__((address_space(1))) const unsigned int gu32;
typedef __attribute__((address_space(3))) unsigned int lu32;

__device__ __forceinline__ void async16(void* lds, const void* g) {
  __builtin_amdgcn_global_load_lds((gu32*)(uintptr_t)g, (lu32*)(uintptr_t)lds, 16, 0, 0);
}

__device__ __forceinline__ unsigned short f2bf(float f) {
  unsigned int u = __float_as_uint(f);
  return (unsigned short)((u + 0x7fffu + ((u >> 16) & 1u)) >> 16);
}
__device__ __forceinline__ float bf2f(unsigned short u) {
  return __uint_as_float(((unsigned int)u) << 16);
}

// ---------------- x fp32 -> bf16 ----------------
__global__ __launch_bounds__(256) void k_cvt_x(const float* __restrict__ x,
                                               unsigned short* __restrict__ x16) {
  int i = blockIdx.x * 256 + threadIdx.x;
  float4 v = reinterpret_cast<const float4*>(x)[i];
  ushort4 o;
  o.x = f2bf(v.x); o.y = f2bf(v.y); o.z = f2bf(v.z); o.w = f2bf(v.w);
  reinterpret_cast<ushort4*>(x16)[i] = o;
}

// ---------------- [E][R][C] fp32 -> [E][C][R] bf16 (tiled transpose) ----------------
__global__ __launch_bounds__(256) void k_transpose(const float* __restrict__ in,
                                                   unsigned short* __restrict__ out,
                                                   int R, int C) {
  __shared__ float t[32][33];
  const size_t mbase = (size_t)blockIdx.z * R * C;
  int tid = threadIdx.x;
  int r = tid >> 3, c4 = (tid & 7) * 4;
  int gr = blockIdx.y * 32 + r;
  int gc = blockIdx.x * 32 + c4;
  float4 v = *reinterpret_cast<const float4*>(in + mbase + (size_t)gr * C + gc);
  t[r][c4 + 0] = v.x; t[r][c4 + 1] = v.y; t[r][c4 + 2] = v.z; t[r][c4 + 3] = v.w;
  __syncthreads();
  int orow = blockIdx.x * 32 + r;    // original col
  int oc4  = blockIdx.y * 32 + c4;   // original row
  ushort4 o;
  o.x = f2bf(t[c4 + 0][r]); o.y = f2bf(t[c4 + 1][r]);
  o.z = f2bf(t[c4 + 2][r]); o.w = f2bf(t[c4 + 3][r]);
  *reinterpret_cast<ushort4*>(out + mbase + (size_t)orow * R + oc4) = o;
}

// ---------------- routing: detect+count+scan+scatter+tilemap in ONE block ----------------
__global__ __launch_bounds__(1024) void k_route(
    const int* __restrict__ idx, const float* __restrict__ ew,
    const int* __restrict__ amask,
    int* __restrict__ counts_g, int* __restrict__ offs_g,
    int* __restrict__ toks, float* __restrict__ wl, int* __restrict__ slotmap,
    int* __restrict__ tiles_g, int* __restrict__ ntiles_g) {
  __shared__ int cnt[NEXP], cur[NEXP], flag;
  const int t = threadIdx.x;
  if (t < NEXP) cnt[t] = 0;
  if (t == 0) flag = 0;
  __syncthreads();
  // dtype detect: if int64, all high (odd) words are 0
  int lf = 0;
#pragma unroll
  for (int j = 0; j < 4; ++j) {
    int i = t + j * 1024;
    if (idx[2 * i + 1] != 0) lf = 1;
  }
  if (lf) atomicOr(&flag, 1);
  __syncthreads();
  const int is32 = flag;
  int e[8];
#pragma unroll
  for (int j = 0; j < 8; ++j) {
    int i = t + j * 1024;
    int ei = is32 ? idx[i] : idx[2 * i];
    e[j] = ei;
    atomicAdd(&cnt[ei], 1);
  }
  __syncthreads();
  if (t == 0) {
    int off = 0, nt_ = 0;
    for (int k = 0; k < NEXP; ++k) {
      cur[k] = off; offs_g[k] = off; counts_g[k] = cnt[k]; off += cnt[k];
      int m = (cnt[k] + 127) >> 7;
      for (int j = 0; j < m; ++j) tiles_g[nt_++] = (k << 16) | j;
    }
    *ntiles_g = nt_;
  }
  __syncthreads();
#pragma unroll
  for (int j = 0; j < 8; ++j) {
    int i = t + j * 1024;
    int n = i >> 1;
    int slot = atomicAdd(&cur[e[j]], 1);
    toks[slot] = n;
    wl[slot] = ew[i] * (amask[n] ? 1.0f : 0.0f);
    slotmap[i] = slot;
  }
}

// ---------------- grouped GEMM1: hid = relu(X[gather] @ down), 2-buf pipelined ----------------
// A: gathered x16 rows [cnt][1024]; B: dnT [e][2048][1024] (k contig). BK=64, 16 K-tiles.
__global__ __launch_bounds__(256, 2) void k_gemm_down(
    const unsigned short* __restrict__ x16, const unsigned short* __restrict__ bT,
    const int* __restrict__ counts, const int* __restrict__ offs,
    const int* __restrict__ toks, unsigned short* __restrict__ hid,
    const int* __restrict__ tiles, const int* __restrict__ ntiles) {
  const int ti = blockIdx.y;
  if (ti >= *ntiles) return;
  const int pk = tiles[ti];
  const int e = pk >> 16;
  const int mt = pk & 0xffff;
  const int cnt = counts[e];
  const int nt = blockIdx.x;
  const int base = offs[e];
  __shared__ alignas(16) char lds[65536];   // A: [2][16KB] @0, B: [2][16KB] @32768
  const int tid = threadIdx.x;
  const int lane = tid & 63;
  const int wave = tid >> 6;
  const int wrow = (tid >> 7) * 64;
  const int wcol = ((tid >> 6) & 1) * 64;

  // staging (verified in R2): LDS linear row-major [128][128B]; global col pre-swizzled
  // so LDS[row][c] = G[row][c ^ ((row&7)<<4)]
  const char* gA[4]; const char* gB[4]; int sOff[4];
  {
    const int swcol = ((lane & 7) << 4) ^ ((lane >> 3) << 4);
#pragma unroll
    for (int it = 0; it < 4; ++it) {
      int row = wave * 32 + it * 8 + (lane >> 3);
      int sl = mt * 128 + row; if (sl >= cnt) sl = cnt - 1;
      gA[it] = (const char*)(x16 + (size_t)toks[base + sl] * HDIM) + swcol;
      gB[it] = (const char*)(bT + (size_t)e * DDIM * HDIM + (size_t)(nt * 128 + row) * HDIM) + swcol;
      sOff[it] = wave * 4096 + it * 1024 + lane * 16;
    }
  }
  const int swz = (lane & 7) << 4;
  const int lo = (lane >> 4) << 4;
  int rowA[4], rowB[4];
#pragma unroll
  for (int m = 0; m < 4; ++m) {
    rowA[m] = (wrow + m * 16 + (lane & 15)) * 128;
    rowB[m] = (wcol + m * 16 + (lane & 15)) * 128;
  }

  // prologue: stage K-tile 0 into buf0
#pragma unroll
  for (int it = 0; it < 4; ++it) {
    async16(lds + sOff[it], gA[it]);
    async16(lds + 32768 + sOff[it], gB[it]);
  }
  asm volatile("s_waitcnt vmcnt(0)" ::: "memory");
  __builtin_amdgcn_s_barrier();

  f32x4 acc[4][4] = {};
  for (int j = 0; j < 16; ++j) {
    char* curA = lds + ((j & 1) << 14);
    char* curB = lds + 32768 + ((j & 1) << 14);
    char* nxtA = lds + ((~j & 1) << 14);
    char* nxtB = lds + 32768 + ((~j & 1) << 14);
    // ---- phase 0: ks=0 ----
    bf16x8 fa[4], fb[4];
    {
      const int cx = lo ^ swz;
#pragma unroll
      for (int m = 0; m < 4; ++m) fa[m] = *reinterpret_cast<const bf16x8*>(curA + rowA[m] + cx);
#pragma unroll
      for (int n = 0; n < 4; ++n) fb[n] = *reinterpret_cast<const bf16x8*>(curB + rowB[n] + cx);
    }
    if (j < 15) {
      const int ko = (j + 1) << 7;   // +128 bytes per K-tile
#pragma unroll
      for (int it = 0; it < 4; ++it) {
        async16(nxtA + sOff[it], gA[it] + ko);
        async16(nxtB + sOff[it], gB[it] + ko);
      }
    }
    __builtin_amdgcn_s_barrier();
    asm volatile("s_waitcnt lgkmcnt(0)" ::: "memory");
    __builtin_amdgcn_sched_barrier(0);
    __builtin_amdgcn_s_setprio(1);
#pragma unroll
    for (int m = 0; m < 4; ++m)
#pragma unroll
      for (int n = 0; n < 4; ++n)
        acc[m][n] = __builtin_amdgcn_mfma_f32_16x16x32_bf16(fa[m], fb[n], acc[m][n], 0, 0, 0);
    __builtin_amdgcn_s_setprio(0);
    __builtin_amdgcn_s_barrier();
    // ---- phase 1: ks=1 ----
    {
      const int cx = (64 | lo) ^ swz;
#pragma unroll
      for (int m = 0; m < 4; ++m) fa[m] = *reinterpret_cast<const bf16x8*>(curA + rowA[m] + cx);
#pragma unroll
      for (int n = 0; n < 4; ++n) fb[n] = *reinterpret_cast<const bf16x8*>(curB + rowB[n] + cx);
    }
    __builtin_amdgcn_s_barrier();
    asm volatile("s_waitcnt lgkmcnt(0)" ::: "memory");
    __builtin_amdgcn_sched_barrier(0);
    __builtin_amdgcn_s_setprio(1);
#pragma unroll
    for (int m = 0; m < 4; ++m)
#pragma unroll
      for (int n = 0; n < 4; ++n)
        acc[m][n] = __builtin_amdgcn_mfma_f32_16x16x32_bf16(fa[m], fb[n], acc[m][n], 0, 0, 0);
    __builtin_amdgcn_s_setprio(0);
    asm volatile("s_waitcnt vmcnt(0)" ::: "memory");   // next tile landed (counted once/K-tile)
    __builtin_amdgcn_s_barrier();
  }

#pragma unroll
  for (int m = 0; m < 4; ++m) {
    int r0 = mt * 128 + wrow + m * 16 + ((lane >> 4) * 4);
#pragma unroll
    for (int j = 0; j < 4; ++j) {
      int r = r0 + j;
      if (r < cnt) {
        unsigned short* dst = hid + (size_t)(base + r) * DDIM + nt * 128 + wcol + (lane & 15);
#pragma unroll
        for (int n = 0; n < 4; ++n) {
          float v = acc[m][n][j];
          dst[n * 16] = f2bf(v > 0.f ? v : 0.f);
        }
      }
    }
  }
}

// ---------------- grouped GEMM2 (K-split 2): yw[ksp][slot] = partial(hid @ up) ----------------
__global__ __launch_bounds__(256, 2) void k_gemm_up(
    const unsigned short* __restrict__ hid, const unsigned short* __restrict__ bT,
    const int* __restrict__ counts, const int* __restrict__ offs,
    unsigned short* __restrict__ yw,
    const int* __restrict__ tiles, const int* __restrict__ ntiles) {
  const int ti = blockIdx.y;
  if (ti >= *ntiles) return;
  const int pk = tiles[ti];
  const int e = pk >> 16;
  const int mt = pk & 0xffff;
  const int cnt = counts[e];
  const int ksp = blockIdx.x >> 3;
  const int nt = blockIdx.x & 7;
  const int base = offs[e];
  __shared__ alignas(16) char lds[65536];
  const int tid = threadIdx.x;
  const int lane = tid & 63;
  const int wave = tid >> 6;
  const int wrow = (tid >> 7) * 64;
  const int wcol = ((tid >> 6) & 1) * 64;

  const char* gA[4]; const char* gB[4]; int sOff[4];
  {
    const int swcol = ((lane & 7) << 4) ^ ((lane >> 3) << 4);
#pragma unroll
    for (int it = 0; it < 4; ++it) {
      int row = wave * 32 + it * 8 + (lane >> 3);
      int sl = mt * 128 + row; if (sl >= cnt) sl = cnt - 1;
      gA[it] = (const char*)(hid + (size_t)(base + sl) * DDIM + ksp * 1024) + swcol;
      gB[it] = (const char*)(bT + (size_t)e * HDIM * DDIM + (size_t)(nt * 128 + row) * DDIM + ksp * 1024) + swcol;
      sOff[it] = wave * 4096 + it * 1024 + lane * 16;
    }
  }
  const int swz = (lane & 7) << 4;
  const int lo = (lane >> 4) << 4;
  int rowA[4], rowB[4];
#pragma unroll
  for (int m = 0; m < 4; ++m) {
    rowA[m] = (wrow + m * 16 + (lane & 15)) * 128;
    rowB[m] = (wcol + m * 16 + (lane & 15)) * 128;
  }

#pragma unroll
  for (int it = 0; it < 4; ++it) {
    async16(lds + sOff[it], gA[it]);
    async16(lds + 32768 + sOff[it], gB[it]);
  }
  asm volatile("s_waitcnt vmcnt(0)" ::: "memory");
  __builtin_amdgcn_s_barrier();

  f32x4 acc[4][4] = {};
  for (int j = 0; j < 16; ++j) {
    char* curA = lds + ((j & 1) << 14);
    char* curB = lds + 32768 + ((j & 1) << 14);
    char* nxtA = lds + ((~j & 1) << 14);
    char* nxtB = lds + 32768 + ((~j & 1) << 14);
    bf16x8 fa[4], fb[4];
    {
      const int cx = lo ^ swz;
#pragma unroll
      for (int m = 0; m < 4; ++m) fa[m] = *reinterpret_cast<const bf16x8*>(curA + rowA[m] + cx);
#pragma unroll
      for (int n = 0; n < 4; ++n) fb[n] = *reinterpret_cast<const bf16x8*>(curB + rowB[n] + cx);
    }
    if (j < 15) {
      const int ko = (j + 1) << 7;
#pragma unroll
      for (int it = 0; it < 4; ++it) {
        async16(nxtA + sOff[it], gA[it] + ko);
        async16(nxtB + sOff[it], gB[it] + ko);
      }
    }
    __builtin_amdgcn_s_barrier();
    asm volatile("s_waitcnt lgkmcnt(0)" ::: "memory");
    __builtin_amdgcn_sched_barrier(0);
    __builtin_amdgcn_s_setprio(1);
#pragma unroll
    for (int m = 0; m < 4; ++m)
#pragma unroll
      for (int n = 0; n < 4; ++n)
        acc[m][n] = __builtin_amdgcn_mfma_f32_16x16x32_bf16(fa[m], fb[n], acc[m][n], 0, 0, 0);
    __builtin_amdgcn_s_setprio(0);
    __builtin_amdgcn_s_barrier();
    {
      const int cx = (64 | lo) ^ swz;
#pragma unroll
      for (int m = 0; m < 4; ++m) fa[m] = *reinterpret_cast<const bf16x8*>(curA + rowA[m] + cx);
#pragma unroll
      for (int n = 0; n < 4; ++n) fb[n] = *reinterpret_cast<const bf16x8*>(curB + rowB[n] + cx);
    }
    __builtin_amdgcn_s_barrier();
    asm volatile("s_waitcnt lgkmcnt(0)" ::: "memory");
    __builtin_amdgcn_sched_barrier(0);
    __builtin_amdgcn_s_setprio(1);
#pragma unroll
    for (int m = 0; m < 4; ++m)
#pragma unroll
      for (int n = 0; n < 4; ++n)
        acc[m][n] = __builtin_amdgcn_mfma_f32_16x16x32_bf16(fa[m], fb[n], acc[m][n], 0, 0, 0);
    __builtin_amdgcn_s_setprio(0);
    asm volatile("s_waitcnt vmcnt(0)" ::: "memory");
    __builtin_amdgcn_s_barrier();
  }

#pragma unroll
  for (int m = 0; m < 4; ++m) {
    int r0 = mt * 128 + wrow + m * 16 + ((lane >> 4) * 4);
#pragma unroll
    for (int j = 0; j < 4; ++j) {
      int r = r0 + j;
      if (r < cnt) {
        unsigned short* dst = yw + ((size_t)ksp * NASS + base + r) * HDIM
                              + nt * 128 + wcol + (lane & 15);
#pragma unroll
        for (int n = 0; n < 4; ++n) dst[n * 16] = f2bf(acc[m][n][j]);
      }
    }
  }
}

// ---------------- combine: out = x + w0*(p00+p01) + w1*(p10+p11) ----------------
__global__ __launch_bounds__(256) void k_combine(
    const float* __restrict__ x, const unsigned short* __restrict__ yw,
    const int* __restrict__ slotmap, const float* __restrict__ wl,
    float* __restrict__ out) {
  const int n = blockIdx.x;
  const int t = threadIdx.x;
  const int s0 = slotmap[2 * n], s1 = slotmap[2 * n + 1];
  const float w0 = wl[s0], w1 = wl[s1];
  float4 xv = reinterpret_cast<const float4*>(x + (size_t)n * HDIM)[t];
  ushort4 a0 = reinterpret_cast<const ushort4*>(yw + (size_t)s0 * HDIM)[t];
  ushort4 a1 = reinterpret_cast<const ushort4*>(yw + ((size_t)NASS + s0) * HDIM)[t];
  ushort4 b0 = reinterpret_cast<const ushort4*>(yw + (size_t)s1 * HDIM)[t];
  ushort4 b1 = reinterpret_cast<const ushort4*>(yw + ((size_t)NASS + s1) * HDIM)[t];
  float4 r;
  r.x = xv.x + w0 * (bf2f(a0.x) + bf2f(a1.x)) + w1 * (bf2f(b0.x) + bf2f(b1.x));
  r.y = xv.y + w0 * (bf2f(a0.y) + bf2f(a1.y)) + w1 * (bf2f(b0.y) + bf2f(b1.y));
  r.z = xv.z + w0 * (bf2f(a0.z) + bf2f(a1.z)) + w1 * (bf2f(b0.z) + bf2f(b1.z));
  r.w = xv.w + w0 * (bf2f(a0.w) + bf2f(a1.w)) + w1 * (bf2f(b0.w) + bf2f(b1.w));
  reinterpret_cast<float4*>(out + (size_t)n * HDIM)[t] = r;
}

extern "C" void kernel_launch(void* const* d_in, const int* in_sizes, int n_in,
                              void* d_out, int out_size, void* d_ws, size_t ws_size,
                              hipStream_t stream) {
  const float* x    = (const float*)d_in[0];
  const int* amask  = (const int*)d_in[1];
  const float* ew   = (const float*)d_in[2];
  const int* cidx   = (const int*)d_in[3];
  const float* dn   = (const float*)d_in[4];
  const float* up   = (const float*)d_in[5];
  float* out        = (float*)d_out;
  char* ws          = (char*)d_ws;

  const size_t X16_OFF = 0;
  const size_t DNT_OFF = X16_OFF + (size_t)NTOK * HDIM * 2;             // 8.4MB
  const size_t UPT_OFF = DNT_OFF + (size_t)NEXP * HDIM * DDIM * 2;      // +33.5MB
  const size_t HID_OFF = UPT_OFF + (size_t)NEXP * HDIM * DDIM * 2;      // +33.5MB
  const size_t MET_OFF = HID_OFF + (size_t)NASS * DDIM * 2;             // +33.5MB

  unsigned short* x16 = (unsigned short*)(ws + X16_OFF);
  unsigned short* dnT = (unsigned short*)(ws + DNT_OFF);
  unsigned short* upT = (unsigned short*)(ws + UPT_OFF);
  unsigned short* hid = (unsigned short*)(ws + HID_OFF);
  // yw ([2][NASS][HDIM] bf16, 33.5MB) aliases dnT: dnT dead after k_gemm_down
  unsigned short* yw  = (unsigned short*)(ws + DNT_OFF);
  int* counts  = (int*)(ws + MET_OFF);
  int* offs    = counts + 8;
  int* toks    = counts + 32;
  float* wl    = (float*)(toks + NASS);
  int* slotmap = (int*)(wl + NASS);
  int* tiles   = slotmap + NASS;
  int* ntiles  = tiles + 128;

  k_cvt_x<<<NTOK * HDIM / 1024, 256, 0, stream>>>(x, x16);
  k_transpose<<<dim3(DDIM / 32, HDIM / 32, NEXP), 256, 0, stream>>>(dn, dnT, HDIM, DDIM);
  k_transpose<<<dim3(HDIM / 32, DDIM / 32, NEXP), 256, 0, stream>>>(up, upT, DDIM, HDIM);
  k_route<<<1, 1024, 0, stream>>>(cidx, ew, amask, counts, offs, toks, wl, slotmap,
                                  tiles, ntiles);
  k_gemm_down<<<dim3(16, MAXT), 256, 0, stream>>>(x16, dnT, counts, offs, toks, hid,
                                                  tiles, ntiles);
  k_gemm_up<<<dim3(16, MAXT), 256, 0, stream>>>(hid, upT, counts, offs, yw,
                                                tiles, ntiles);
  k_combine<<<NTOK, 256, 0, stream>>>(x, yw, slotmap, wl, out);
}

// Round 6
// 174.368 us; speedup vs baseline: 1.0933x; 1.0173x over previous
//
#include <hip/hip_runtime.h>
#include <stdint.h>

#define NTOK 4096
#define HDIM 1024
#define DDIM 2048
#define NEXP 8
#define NASS 8192   // NTOK * K (K=2)
#define MAXT 72     // worst-case sum_e ceil(cnt_e/128) = 64 + 7

typedef __attribute__((ext_vector_type(8))) short bf16x8;
typedef __attribute__((ext_vector_type(4))) float f32x4;

typedef __attribute__((address_space(1))) const unsigned int gu32;
typedef __attribute__((address_space(3))) unsigned int lu32;

// barrier that is ALSO a compiler memory fence (raw builtin is not; R5 raced)
#define BARRIER() asm volatile("s_barrier" ::: "memory")

__device__ __forceinline__ void async16(void* lds, const void* g) {
  __builtin_amdgcn_global_load_lds((gu32*)(uintptr_t)g, (lu32*)(uintptr_t)lds, 16, 0, 0);
}

__device__ __forceinline__ unsigned short f2bf(float f) {
  unsigned int u = __float_as_uint(f);
  return (unsigned short)((u + 0x7fffu + ((u >> 16) & 1u)) >> 16);
}
__device__ __forceinline__ float bf2f(unsigned short u) {
  return __uint_as_float(((unsigned int)u) << 16);
}

// ---------------- x fp32 -> bf16 ----------------
__global__ __launch_bounds__(256) void k_cvt_x(const float* __restrict__ x,
                                               unsigned short* __restrict__ x16) {
  int i = blockIdx.x * 256 + threadIdx.x;
  float4 v = reinterpret_cast<const float4*>(x)[i];
  ushort4 o;
  o.x = f2bf(v.x); o.y = f2bf(v.y); o.z = f2bf(v.z); o.w = f2bf(v.w);
  reinterpret_cast<ushort4*>(x16)[i] = o;
}

// ---------------- [E][R][C] fp32 -> [E][C][R] bf16 (tiled transpose) ----------------
__global__ __launch_bounds__(256) void k_transpose(const float* __restrict__ in,
                                                   unsigned short* __restrict__ out,
                                                   int R, int C) {
  __shared__ float t[32][33];
  const size_t mbase = (size_t)blockIdx.z * R * C;
  int tid = threadIdx.x;
  int r = tid >> 3, c4 = (tid & 7) * 4;
  int gr = blockIdx.y * 32 + r;
  int gc = blockIdx.x * 32 + c4;
  float4 v = *reinterpret_cast<const float4*>(in + mbase + (size_t)gr * C + gc);
  t[r][c4 + 0] = v.x; t[r][c4 + 1] = v.y; t[r][c4 + 2] = v.z; t[r][c4 + 3] = v.w;
  __syncthreads();
  int orow = blockIdx.x * 32 + r;    // original col
  int oc4  = blockIdx.y * 32 + c4;   // original row
  ushort4 o;
  o.x = f2bf(t[c4 + 0][r]); o.y = f2bf(t[c4 + 1][r]);
  o.z = f2bf(t[c4 + 2][r]); o.w = f2bf(t[c4 + 3][r]);
  *reinterpret_cast<ushort4*>(out + mbase + (size_t)orow * R + oc4) = o;
}

// ---------------- routing: detect+count+scan+scatter+tilemap in ONE block ----------------
__global__ __launch_bounds__(1024) void k_route(
    const int* __restrict__ idx, const float* __restrict__ ew,
    const int* __restrict__ amask,
    int* __restrict__ counts_g, int* __restrict__ offs_g,
    int* __restrict__ toks, float* __restrict__ wl, int* __restrict__ slotmap,
    int* __restrict__ tiles_g, int* __restrict__ ntiles_g) {
  __shared__ int cnt[NEXP], cur[NEXP], flag;
  const int t = threadIdx.x;
  if (t < NEXP) cnt[t] = 0;
  if (t == 0) flag = 0;
  __syncthreads();
  // dtype detect: if int64, all high (odd) words are 0
  int lf = 0;
#pragma unroll
  for (int j = 0; j < 4; ++j) {
    int i = t + j * 1024;
    if (idx[2 * i + 1] != 0) lf = 1;
  }
  if (lf) atomicOr(&flag, 1);
  __syncthreads();
  const int is32 = flag;
  int e[8];
#pragma unroll
  for (int j = 0; j < 8; ++j) {
    int i = t + j * 1024;
    int ei = is32 ? idx[i] : idx[2 * i];
    e[j] = ei;
    atomicAdd(&cnt[ei], 1);
  }
  __syncthreads();
  if (t == 0) {
    int off = 0, nt_ = 0;
    for (int k = 0; k < NEXP; ++k) {
      cur[k] = off; offs_g[k] = off; counts_g[k] = cnt[k]; off += cnt[k];
      int m = (cnt[k] + 127) >> 7;
      for (int j = 0; j < m; ++j) tiles_g[nt_++] = (k << 16) | j;
    }
    *ntiles_g = nt_;
  }
  __syncthreads();
#pragma unroll
  for (int j = 0; j < 8; ++j) {
    int i = t + j * 1024;
    int n = i >> 1;
    int slot = atomicAdd(&cur[e[j]], 1);
    toks[slot] = n;
    wl[slot] = ew[i] * (amask[n] ? 1.0f : 0.0f);
    slotmap[i] = slot;
  }
}

// ---------------- grouped GEMM1: hid = relu(X[gather] @ down) ----------------
// 512 threads, 8 waves (2M x 4N, each 64x32), 128x128 tile, BK=64, dbuf pipeline.
__global__ __launch_bounds__(512, 4) void k_gemm_down(
    const unsigned short* __restrict__ x16, const unsigned short* __restrict__ bT,
    const int* __restrict__ counts, const int* __restrict__ offs,
    const int* __restrict__ toks, unsigned short* __restrict__ hid,
    const int* __restrict__ tiles, const int* __restrict__ ntiles) {
  const int ti = blockIdx.y;
  if (ti >= *ntiles) return;
  const int pk = tiles[ti];
  const int e = pk >> 16;
  const int mt = pk & 0xffff;
  const int cnt = counts[e];
  const int nt = blockIdx.x;
  const int base = offs[e];
  __shared__ alignas(16) char lds[65536];   // A: [2][16KB] @0, B: [2][16KB] @32768
  const int tid = threadIdx.x;
  const int lane = tid & 63;
  const int wr = ((tid >> 8) & 1) * 64;     // wave row block (2)
  const int wc = ((tid >> 6) & 3) * 32;     // wave col block (4)

  // staging: LDS linear [128 rows][128B]; global col pre-swizzled so
  // LDS[row][c] = G[row][c ^ ((row&7)<<4)]   (rule #21)
  const char* gA[2]; const char* gB[2]; int sOff[2];
  {
    const int swcol = ((tid & 7) << 4) ^ (((tid >> 3) & 7) << 4);
#pragma unroll
    for (int it = 0; it < 2; ++it) {
      int row = it * 64 + (tid >> 3);
      int sl = mt * 128 + row; if (sl >= cnt) sl = cnt - 1;
      gA[it] = (const char*)(x16 + (size_t)toks[base + sl] * HDIM) + swcol;
      gB[it] = (const char*)(bT + (size_t)e * DDIM * HDIM + (size_t)(nt * 128 + row) * HDIM) + swcol;
      sOff[it] = it * 8192 + tid * 16;
    }
  }
  const int swz = (lane & 7) << 4;
  const int lo = (lane >> 4) << 4;
  int rowA[4], rowB[2];
#pragma unroll
  for (int m = 0; m < 4; ++m) rowA[m] = (wr + m * 16 + (lane & 15)) * 128;
#pragma unroll
  for (int n = 0; n < 2; ++n) rowB[n] = (wc + n * 16 + (lane & 15)) * 128;

  // prologue: stage K-tile 0 into buf0
#pragma unroll
  for (int it = 0; it < 2; ++it) {
    async16(lds + sOff[it], gA[it]);
    async16(lds + 32768 + sOff[it], gB[it]);
  }
  asm volatile("s_waitcnt vmcnt(0)" ::: "memory");
  BARRIER();

  f32x4 acc[4][2] = {};
  for (int j = 0; j < 16; ++j) {
    char* curA = lds + ((j & 1) << 14);
    char* curB = lds + 32768 + ((j & 1) << 14);
    char* nxtA = lds + ((~j & 1) << 14);
    char* nxtB = lds + 32768 + ((~j & 1) << 14);
    // ---- phase 0: ks=0 ----
    bf16x8 fa[4], fb[2];
    {
      const int cx = lo ^ swz;
#pragma unroll
      for (int m = 0; m < 4; ++m) fa[m] = *reinterpret_cast<const bf16x8*>(curA + rowA[m] + cx);
#pragma unroll
      for (int n = 0; n < 2; ++n) fb[n] = *reinterpret_cast<const bf16x8*>(curB + rowB[n] + cx);
    }
    if (j < 15) {
      const int ko = (j + 1) << 7;   // +128 bytes per K-tile
#pragma unroll
      for (int it = 0; it < 2; ++it) {
        async16(nxtA + sOff[it], gA[it] + ko);
        async16(nxtB + sOff[it], gB[it] + ko);
      }
    }
    BARRIER();
    asm volatile("s_waitcnt lgkmcnt(0)" ::: "memory");
    __builtin_amdgcn_sched_barrier(0);
    __builtin_amdgcn_s_setprio(1);
#pragma unroll
    for (int m = 0; m < 4; ++m)
#pragma unroll
      for (int n = 0; n < 2; ++n)
        acc[m][n] = __builtin_amdgcn_mfma_f32_16x16x32_bf16(fa[m], fb[n], acc[m][n], 0, 0, 0);
    __builtin_amdgcn_s_setprio(0);
    BARRIER();
    // ---- phase 1: ks=1 ----
    {
      const int cx = (64 | lo) ^ swz;
#pragma unroll
      for (int m = 0; m < 4; ++m) fa[m] = *reinterpret_cast<const bf16x8*>(curA + rowA[m] + cx);
#pragma unroll
      for (int n = 0; n < 2; ++n) fb[n] = *reinterpret_cast<const bf16x8*>(curB + rowB[n] + cx);
    }
    BARRIER();
    asm volatile("s_waitcnt lgkmcnt(0)" ::: "memory");
    __builtin_amdgcn_sched_barrier(0);
    __builtin_amdgcn_s_setprio(1);
#pragma unroll
    for (int m = 0; m < 4; ++m)
#pragma unroll
      for (int n = 0; n < 2; ++n)
        acc[m][n] = __builtin_amdgcn_mfma_f32_16x16x32_bf16(fa[m], fb[n], acc[m][n], 0, 0, 0);
    __builtin_amdgcn_s_setprio(0);
    asm volatile("s_waitcnt vmcnt(0)" ::: "memory");   // next tile landed
    BARRIER();
  }

#pragma unroll
  for (int m = 0; m < 4; ++m) {
    int r0 = mt * 128 + wr + m * 16 + ((lane >> 4) * 4);
#pragma unroll
    for (int j = 0; j < 4; ++j) {
      int r = r0 + j;
      if (r < cnt) {
        unsigned short* dst = hid + (size_t)(base + r) * DDIM + nt * 128 + wc + (lane & 15);
#pragma unroll
        for (int n = 0; n < 2; ++n) {
          float v = acc[m][n][j];
          dst[n * 16] = f2bf(v > 0.f ? v : 0.f);
        }
      }
    }
  }
}

// ---------------- grouped GEMM2: yw[slot] = hid[slot] @ up  (K=2048, no split) ----------------
__global__ __launch_bounds__(512, 4) void k_gemm_up(
    const unsigned short* __restrict__ hid, const unsigned short* __restrict__ bT,
    const int* __restrict__ counts, const int* __restrict__ offs,
    unsigned short* __restrict__ yw,
    const int* __restrict__ tiles, const int* __restrict__ ntiles) {
  const int ti = blockIdx.y;
  if (ti >= *ntiles) return;
  const int pk = tiles[ti];
  const int e = pk >> 16;
  const int mt = pk & 0xffff;
  const int cnt = counts[e];
  const int nt = blockIdx.x;        // 0..7
  const int base = offs[e];
  __shared__ alignas(16) char lds[65536];
  const int tid = threadIdx.x;
  const int lane = tid & 63;
  const int wr = ((tid >> 8) & 1) * 64;
  const int wc = ((tid >> 6) & 3) * 32;

  const char* gA[2]; const char* gB[2]; int sOff[2];
  {
    const int swcol = ((tid & 7) << 4) ^ (((tid >> 3) & 7) << 4);
#pragma unroll
    for (int it = 0; it < 2; ++it) {
      int row = it * 64 + (tid >> 3);
      int sl = mt * 128 + row; if (sl >= cnt) sl = cnt - 1;
      gA[it] = (const char*)(hid + (size_t)(base + sl) * DDIM) + swcol;
      gB[it] = (const char*)(bT + (size_t)e * HDIM * DDIM + (size_t)(nt * 128 + row) * DDIM) + swcol;
      sOff[it] = it * 8192 + tid * 16;
    }
  }
  const int swz = (lane & 7) << 4;
  const int lo = (lane >> 4) << 4;
  int rowA[4], rowB[2];
#pragma unroll
  for (int m = 0; m < 4; ++m) rowA[m] = (wr + m * 16 + (lane & 15)) * 128;
#pragma unroll
  for (int n = 0; n < 2; ++n) rowB[n] = (wc + n * 16 + (lane & 15)) * 128;

#pragma unroll
  for (int it = 0; it < 2; ++it) {
    async16(lds + sOff[it], gA[it]);
    async16(lds + 32768 + sOff[it], gB[it]);
  }
  asm volatile("s_waitcnt vmcnt(0)" ::: "memory");
  BARRIER();

  f32x4 acc[4][2] = {};
  for (int j = 0; j < 32; ++j) {
    char* curA = lds + ((j & 1) << 14);
    char* curB = lds + 32768 + ((j & 1) << 14);
    char* nxtA = lds + ((~j & 1) << 14);
    char* nxtB = lds + 32768 + ((~j & 1) << 14);
    bf16x8 fa[4], fb[2];
    {
      const int cx = lo ^ swz;
#pragma unroll
      for (int m = 0; m < 4; ++m) fa[m] = *reinterpret_cast<const bf16x8*>(curA + rowA[m] + cx);
#pragma unroll
      for (int n = 0; n < 2; ++n) fb[n] = *reinterpret_cast<const bf16x8*>(curB + rowB[n] + cx);
    }
    if (j < 31) {
      const int ko = (j + 1) << 7;
#pragma unroll
      for (int it = 0; it < 2; ++it) {
        async16(nxtA + sOff[it], gA[it] + ko);
        async16(nxtB + sOff[it], gB[it] + ko);
      }
    }
    BARRIER();
    asm volatile("s_waitcnt lgkmcnt(0)" ::: "memory");
    __builtin_amdgcn_sched_barrier(0);
    __builtin_amdgcn_s_setprio(1);
#pragma unroll
    for (int m = 0; m < 4; ++m)
#pragma unroll
      for (int n = 0; n < 2; ++n)
        acc[m][n] = __builtin_amdgcn_mfma_f32_16x16x32_bf16(fa[m], fb[n], acc[m][n], 0, 0, 0);
    __builtin_amdgcn_s_setprio(0);
    BARRIER();
    {
      const int cx = (64 | lo) ^ swz;
#pragma unroll
      for (int m = 0; m < 4; ++m) fa[m] = *reinterpret_cast<const bf16x8*>(curA + rowA[m] + cx);
#pragma unroll
      for (int n = 0; n < 2; ++n) fb[n] = *reinterpret_cast<const bf16x8*>(curB + rowB[n] + cx);
    }
    BARRIER();
    asm volatile("s_waitcnt lgkmcnt(0)" ::: "memory");
    __builtin_amdgcn_sched_barrier(0);
    __builtin_amdgcn_s_setprio(1);
#pragma unroll
    for (int m = 0; m < 4; ++m)
#pragma unroll
      for (int n = 0; n < 2; ++n)
        acc[m][n] = __builtin_amdgcn_mfma_f32_16x16x32_bf16(fa[m], fb[n], acc[m][n], 0, 0, 0);
    __builtin_amdgcn_s_setprio(0);
    asm volatile("s_waitcnt vmcnt(0)" ::: "memory");
    BARRIER();
  }

#pragma unroll
  for (int m = 0; m < 4; ++m) {
    int r0 = mt * 128 + wr + m * 16 + ((lane >> 4) * 4);
#pragma unroll
    for (int j = 0; j < 4; ++j) {
      int r = r0 + j;
      if (r < cnt) {
        unsigned short* dst = yw + (size_t)(base + r) * HDIM + nt * 128 + wc + (lane & 15);
#pragma unroll
        for (int n = 0; n < 2; ++n) dst[n * 16] = f2bf(acc[m][n][j]);
      }
    }
  }
}

// ---------------- combine: out = x + w0*y0 + w1*y1 ----------------
__global__ __launch_bounds__(256) void k_combine(
    const float* __restrict__ x, const unsigned short* __restrict__ yw,
    const int* __restrict__ slotmap, const float* __restrict__ wl,
    float* __restrict__ out) {
  const int n = blockIdx.x;
  const int t = threadIdx.x;
  const int s0 = slotmap[2 * n], s1 = slotmap[2 * n + 1];
  const float w0 = wl[s0], w1 = wl[s1];
  float4 xv = reinterpret_cast<const float4*>(x + (size_t)n * HDIM)[t];
  ushort4 a0 = reinterpret_cast<const ushort4*>(yw + (size_t)s0 * HDIM)[t];
  ushort4 b0 = reinterpret_cast<const ushort4*>(yw + (size_t)s1 * HDIM)[t];
  float4 r;
  r.x = xv.x + w0 * bf2f(a0.x) + w1 * bf2f(b0.x);
  r.y = xv.y + w0 * bf2f(a0.y) + w1 * bf2f(b0.y);
  r.z = xv.z + w0 * bf2f(a0.z) + w1 * bf2f(b0.z);
  r.w = xv.w + w0 * bf2f(a0.w) + w1 * bf2f(b0.w);
  reinterpret_cast<float4*>(out + (size_t)n * HDIM)[t] = r;
}

extern "C" void kernel_launch(void* const* d_in, const int* in_sizes, int n_in,
                              void* d_out, int out_size, void* d_ws, size_t ws_size,
                              hipStream_t stream) {
  const float* x    = (const float*)d_in[0];
  const int* amask  = (const int*)d_in[1];
  const float* ew   = (const float*)d_in[2];
  const int* cidx   = (const int*)d_in[3];
  const float* dn   = (const float*)d_in[4];
  const float* up   = (const float*)d_in[5];
  float* out        = (float*)d_out;
  char* ws          = (char*)d_ws;

  const size_t X16_OFF = 0;
  const size_t DNT_OFF = X16_OFF + (size_t)NTOK * HDIM * 2;             // 8.4MB
  const size_t UPT_OFF = DNT_OFF + (size_t)NEXP * HDIM * DDIM * 2;      // +33.5MB
  const size_t HID_OFF = UPT_OFF + (size_t)NEXP * HDIM * DDIM * 2;      // +33.5MB
  const size_t MET_OFF = HID_OFF + (size_t)NASS * DDIM * 2;             // +33.5MB

  unsigned short* x16 = (unsigned short*)(ws + X16_OFF);
  unsigned short* dnT = (unsigned short*)(ws + DNT_OFF);
  unsigned short* upT = (unsigned short*)(ws + UPT_OFF);
  unsigned short* hid = (unsigned short*)(ws + HID_OFF);
  // yw ([NASS][HDIM] bf16, 16.8MB) aliases dnT: dnT dead after k_gemm_down
  unsigned short* yw  = (unsigned short*)(ws + DNT_OFF);
  int* counts  = (int*)(ws + MET_OFF);
  int* offs    = counts + 8;
  int* toks    = counts + 32;
  float* wl    = (float*)(toks + NASS);
  int* slotmap = (int*)(wl + NASS);
  int* tiles   = slotmap + NASS;
  int* ntiles  = tiles + 128;

  k_cvt_x<<<NTOK * HDIM / 1024, 256, 0, stream>>>(x, x16);
  k_transpose<<<dim3(DDIM / 32, HDIM / 32, NEXP), 256, 0, stream>>>(dn, dnT, HDIM, DDIM);
  k_transpose<<<dim3(HDIM / 32, DDIM / 32, NEXP), 256, 0, stream>>>(up, upT, DDIM, HDIM);
  k_route<<<1, 1024, 0, stream>>>(cidx, ew, amask, counts, offs, toks, wl, slotmap,
                                  tiles, ntiles);
  k_gemm_down<<<dim3(16, MAXT), 512, 0, stream>>>(x16, dnT, counts, offs, toks, hid,
                                                  tiles, ntiles);
  k_gemm_up<<<dim3(8, MAXT), 512, 0, stream>>>(hid, upT, counts, offs, yw,
                                               tiles, ntiles);
  k_combine<<<NTOK, 256, 0, stream>>>(x, yw, slotmap, wl, out);
}

// Round 7
// 157.554 us; speedup vs baseline: 1.2100x; 1.1067x over previous
//
#include <hip/hip_runtime.h>
#include <stdint.h>

#define NTOK 4096
#define HDIM 1024
#define DDIM 2048
#define NEXP 8
#define NASS 8192   // NTOK * K (K=2)

typedef __attribute__((ext_vector_type(8))) short bf16x8;
typedef __attribute__((ext_vector_type(4))) float f32x4;

typedef __attribute__((address_space(1))) const unsigned int gu32;
typedef __attribute__((address_space(3))) unsigned int lu32;

// barrier that is ALSO a compiler memory fence (raw builtin is not; R5 raced)
#define BARRIER() asm volatile("s_barrier" ::: "memory")

__device__ __forceinline__ void async16(void* lds, const void* g) {
  __builtin_amdgcn_global_load_lds((gu32*)(uintptr_t)g, (lu32*)(uintptr_t)lds, 16, 0, 0);
}

__device__ __forceinline__ unsigned short f2bf(float f) {
  unsigned int u = __float_as_uint(f);
  return (unsigned short)((u + 0x7fffu + ((u >> 16) & 1u)) >> 16);
}
__device__ __forceinline__ float bf2f(unsigned short u) {
  return __uint_as_float(((unsigned int)u) << 16);
}

// ---------------- x fp32 -> bf16 ----------------
__global__ __launch_bounds__(256) void k_cvt_x(const float* __restrict__ x,
                                               unsigned short* __restrict__ x16) {
  int i = blockIdx.x * 256 + threadIdx.x;
  float4 v = reinterpret_cast<const float4*>(x)[i];
  ushort4 o;
  o.x = f2bf(v.x); o.y = f2bf(v.y); o.z = f2bf(v.z); o.w = f2bf(v.w);
  reinterpret_cast<ushort4*>(x16)[i] = o;
}

// ---------------- [E][R][C] fp32 -> [E][C][R] bf16 (tiled transpose) ----------------
__global__ __launch_bounds__(256) void k_transpose(const float* __restrict__ in,
                                                   unsigned short* __restrict__ out,
                                                   int R, int C) {
  __shared__ float t[32][33];
  const size_t mbase = (size_t)blockIdx.z * R * C;
  int tid = threadIdx.x;
  int r = tid >> 3, c4 = (tid & 7) * 4;
  int gr = blockIdx.y * 32 + r;
  int gc = blockIdx.x * 32 + c4;
  float4 v = *reinterpret_cast<const float4*>(in + mbase + (size_t)gr * C + gc);
  t[r][c4 + 0] = v.x; t[r][c4 + 1] = v.y; t[r][c4 + 2] = v.z; t[r][c4 + 3] = v.w;
  __syncthreads();
  int orow = blockIdx.x * 32 + r;    // original col
  int oc4  = blockIdx.y * 32 + c4;   // original row
  ushort4 o;
  o.x = f2bf(t[c4 + 0][r]); o.y = f2bf(t[c4 + 1][r]);
  o.z = f2bf(t[c4 + 2][r]); o.w = f2bf(t[c4 + 3][r]);
  *reinterpret_cast<ushort4*>(out + mbase + (size_t)orow * R + oc4) = o;
}

// ---------------- routing: detect+count+scan+scatter in ONE block ----------------
__global__ __launch_bounds__(1024) void k_route(
    const int* __restrict__ idx, const float* __restrict__ ew,
    const int* __restrict__ amask,
    int* __restrict__ counts_g, int* __restrict__ offs_g,
    int* __restrict__ toks, float* __restrict__ wl, int* __restrict__ slotmap) {
  __shared__ int cnt[NEXP], cur[NEXP], flag;
  const int t = threadIdx.x;
  if (t < NEXP) cnt[t] = 0;
  if (t == 0) flag = 0;
  __syncthreads();
  // dtype detect: if int64, all high (odd) words are 0
  int lf = 0;
#pragma unroll
  for (int j = 0; j < 4; ++j) {
    int i = t + j * 1024;
    if (idx[2 * i + 1] != 0) lf = 1;
  }
  if (lf) atomicOr(&flag, 1);
  __syncthreads();
  const int is32 = flag;
  int e[8];
#pragma unroll
  for (int j = 0; j < 8; ++j) {
    int i = t + j * 1024;
    int ei = is32 ? idx[i] : idx[2 * i];
    e[j] = ei;
    atomicAdd(&cnt[ei], 1);
  }
  __syncthreads();
  if (t == 0) {
    int off = 0;
    for (int k = 0; k < NEXP; ++k) {
      cur[k] = off; offs_g[k] = off; counts_g[k] = cnt[k]; off += cnt[k];
    }
  }
  __syncthreads();
#pragma unroll
  for (int j = 0; j < 8; ++j) {
    int i = t + j * 1024;
    int n = i >> 1;
    int slot = atomicAdd(&cur[e[j]], 1);
    toks[slot] = n;
    wl[slot] = ew[i] * (amask[n] ? 1.0f : 0.0f);
    slotmap[i] = slot;
  }
}

// ---------------- grouped GEMM1: hid = relu(X[gather] @ down) ----------------
// 512 threads, 8 waves (2M x 4N, each 64x32), 128x128 tile, BK=64, dbuf pipeline.
// Expert->XCD colocation: blockIdx.x == XCD == expert (round-robin dispatch).
__global__ __launch_bounds__(512, 4) void k_gemm_down(
    const unsigned short* __restrict__ x16, const unsigned short* __restrict__ bT,
    const int* __restrict__ counts, const int* __restrict__ offs,
    const int* __restrict__ toks, unsigned short* __restrict__ hid) {
  const int e = blockIdx.x;                 // expert == XCD
  const int cnt = counts[e];
  const int q = blockIdx.y;
  const int mt = q >> 4;                    // 0..63 capacity
  const int nt = q & 15;                    // 0..15
  if (mt * 128 >= cnt) return;
  const int base = offs[e];
  __shared__ alignas(16) char lds[65536];   // A: [2][16KB] @0, B: [2][16KB] @32768
  const int tid = threadIdx.x;
  const int lane = tid & 63;
  const int wr = ((tid >> 8) & 1) * 64;     // wave row block (2)
  const int wc = ((tid >> 6) & 3) * 32;     // wave col block (4)

  // staging: LDS linear [128 rows][128B]; global col pre-swizzled so
  // LDS[row][c] = G[row][c ^ ((row&7)<<4)]   (rule #21)
  const char* gA[2]; const char* gB[2]; int sOff[2];
  {
    const int swcol = ((tid & 7) << 4) ^ (((tid >> 3) & 7) << 4);
#pragma unroll
    for (int it = 0; it < 2; ++it) {
      int row = it * 64 + (tid >> 3);
      int sl = mt * 128 + row; if (sl >= cnt) sl = cnt - 1;
      gA[it] = (const char*)(x16 + (size_t)toks[base + sl] * HDIM) + swcol;
      gB[it] = (const char*)(bT + (size_t)e * DDIM * HDIM + (size_t)(nt * 128 + row) * HDIM) + swcol;
      sOff[it] = it * 8192 + tid * 16;
    }
  }
  const int swz = (lane & 7) << 4;
  const int lo = (lane >> 4) << 4;
  int rowA[4], rowB[2];
#pragma unroll
  for (int m = 0; m < 4; ++m) rowA[m] = (wr + m * 16 + (lane & 15)) * 128;
#pragma unroll
  for (int n = 0; n < 2; ++n) rowB[n] = (wc + n * 16 + (lane & 15)) * 128;

  // prologue: stage K-tile 0 into buf0
#pragma unroll
  for (int it = 0; it < 2; ++it) {
    async16(lds + sOff[it], gA[it]);
    async16(lds + 32768 + sOff[it], gB[it]);
  }
  asm volatile("s_waitcnt vmcnt(0)" ::: "memory");
  BARRIER();

  f32x4 acc[4][2] = {};
  for (int j = 0; j < 16; ++j) {
    char* curA = lds + ((j & 1) << 14);
    char* curB = lds + 32768 + ((j & 1) << 14);
    char* nxtA = lds + ((~j & 1) << 14);
    char* nxtB = lds + 32768 + ((~j & 1) << 14);
    // ---- phase 0: ks=0 ----
    bf16x8 fa[4], fb[2];
    {
      const int cx = lo ^ swz;
#pragma unroll
      for (int m = 0; m < 4; ++m) fa[m] = *reinterpret_cast<const bf16x8*>(curA + rowA[m] + cx);
#pragma unroll
      for (int n = 0; n < 2; ++n) fb[n] = *reinterpret_cast<const bf16x8*>(curB + rowB[n] + cx);
    }
    if (j < 15) {
      const int ko = (j + 1) << 7;   // +128 bytes per K-tile
#pragma unroll
      for (int it = 0; it < 2; ++it) {
        async16(nxtA + sOff[it], gA[it] + ko);
        async16(nxtB + sOff[it], gB[it] + ko);
      }
    }
    BARRIER();
    asm volatile("s_waitcnt lgkmcnt(0)" ::: "memory");
    __builtin_amdgcn_sched_barrier(0);
    __builtin_amdgcn_s_setprio(1);
#pragma unroll
    for (int m = 0; m < 4; ++m)
#pragma unroll
      for (int n = 0; n < 2; ++n)
        acc[m][n] = __builtin_amdgcn_mfma_f32_16x16x32_bf16(fa[m], fb[n], acc[m][n], 0, 0, 0);
    __builtin_amdgcn_s_setprio(0);
    BARRIER();
    // ---- phase 1: ks=1 ----
    {
      const int cx = (64 | lo) ^ swz;
#pragma unroll
      for (int m = 0; m < 4; ++m) fa[m] = *reinterpret_cast<const bf16x8*>(curA + rowA[m] + cx);
#pragma unroll
      for (int n = 0; n < 2; ++n) fb[n] = *reinterpret_cast<const bf16x8*>(curB + rowB[n] + cx);
    }
    BARRIER();
    asm volatile("s_waitcnt lgkmcnt(0)" ::: "memory");
    __builtin_amdgcn_sched_barrier(0);
    __builtin_amdgcn_s_setprio(1);
#pragma unroll
    for (int m = 0; m < 4; ++m)
#pragma unroll
      for (int n = 0; n < 2; ++n)
        acc[m][n] = __builtin_amdgcn_mfma_f32_16x16x32_bf16(fa[m], fb[n], acc[m][n], 0, 0, 0);
    __builtin_amdgcn_s_setprio(0);
    asm volatile("s_waitcnt vmcnt(0)" ::: "memory");   // next tile landed
    BARRIER();
  }

#pragma unroll
  for (int m = 0; m < 4; ++m) {
    int r0 = mt * 128 + wr + m * 16 + ((lane >> 4) * 4);
#pragma unroll
    for (int j = 0; j < 4; ++j) {
      int r = r0 + j;
      if (r < cnt) {
        unsigned short* dst = hid + (size_t)(base + r) * DDIM + nt * 128 + wc + (lane & 15);
#pragma unroll
        for (int n = 0; n < 2; ++n) {
          float v = acc[m][n][j];
          dst[n * 16] = f2bf(v > 0.f ? v : 0.f);
        }
      }
    }
  }
}

// ---------------- grouped GEMM2: yw[slot] = hid[slot] @ up  (K=2048) ----------------
// Expert->XCD colocation: blockIdx.x == XCD == expert.
__global__ __launch_bounds__(512, 4) void k_gemm_up(
    const unsigned short* __restrict__ hid, const unsigned short* __restrict__ bT,
    const int* __restrict__ counts, const int* __restrict__ offs,
    unsigned short* __restrict__ yw) {
  const int e = blockIdx.x;                 // expert == XCD
  const int cnt = counts[e];
  const int q = blockIdx.y;
  const int mt = q >> 3;                    // 0..63 capacity
  const int nt = q & 7;                     // 0..7
  if (mt * 128 >= cnt) return;
  const int base = offs[e];
  __shared__ alignas(16) char lds[65536];
  const int tid = threadIdx.x;
  const int lane = tid & 63;
  const int wr = ((tid >> 8) & 1) * 64;
  const int wc = ((tid >> 6) & 3) * 32;

  const char* gA[2]; const char* gB[2]; int sOff[2];
  {
    const int swcol = ((tid & 7) << 4) ^ (((tid >> 3) & 7) << 4);
#pragma unroll
    for (int it = 0; it < 2; ++it) {
      int row = it * 64 + (tid >> 3);
      int sl = mt * 128 + row; if (sl >= cnt) sl = cnt - 1;
      gA[it] = (const char*)(hid + (size_t)(base + sl) * DDIM) + swcol;
      gB[it] = (const char*)(bT + (size_t)e * HDIM * DDIM + (size_t)(nt * 128 + row) * DDIM) + swcol;
      sOff[it] = it * 8192 + tid * 16;
    }
  }
  const int swz = (lane & 7) << 4;
  const int lo = (lane >> 4) << 4;
  int rowA[4], rowB[2];
#pragma unroll
  for (int m = 0; m < 4; ++m) rowA[m] = (wr + m * 16 + (lane & 15)) * 128;
#pragma unroll
  for (int n = 0; n < 2; ++n) rowB[n] = (wc + n * 16 + (lane & 15)) * 128;

#pragma unroll
  for (int it = 0; it < 2; ++it) {
    async16(lds + sOff[it], gA[it]);
    async16(lds + 32768 + sOff[it], gB[it]);
  }
  asm volatile("s_waitcnt vmcnt(0)" ::: "memory");
  BARRIER();

  f32x4 acc[4][2] = {};
  for (int j = 0; j < 32; ++j) {
    char* curA = lds + ((j & 1) << 14);
    char* curB = lds + 32768 + ((j & 1) << 14);
    char* nxtA = lds + ((~j & 1) << 14);
    char* nxtB = lds + 32768 + ((~j & 1) << 14);
    bf16x8 fa[4], fb[2];
    {
      const int cx = lo ^ swz;
#pragma unroll
      for (int m = 0; m < 4; ++m) fa[m] = *reinterpret_cast<const bf16x8*>(curA + rowA[m] + cx);
#pragma unroll
      for (int n = 0; n < 2; ++n) fb[n] = *reinterpret_cast<const bf16x8*>(curB + rowB[n] + cx);
    }
    if (j < 31) {
      const int ko = (j + 1) << 7;
#pragma unroll
      for (int it = 0; it < 2; ++it) {
        async16(nxtA + sOff[it], gA[it] + ko);
        async16(nxtB + sOff[it], gB[it] + ko);
      }
    }
    BARRIER();
    asm volatile("s_waitcnt lgkmcnt(0)" ::: "memory");
    __builtin_amdgcn_sched_barrier(0);
    __builtin_amdgcn_s_setprio(1);
#pragma unroll
    for (int m = 0; m < 4; ++m)
#pragma unroll
      for (int n = 0; n < 2; ++n)
        acc[m][n] = __builtin_amdgcn_mfma_f32_16x16x32_bf16(fa[m], fb[n], acc[m][n], 0, 0, 0);
    __builtin_amdgcn_s_setprio(0);
    BARRIER();
    {
      const int cx = (64 | lo) ^ swz;
#pragma unroll
      for (int m = 0; m < 4; ++m) fa[m] = *reinterpret_cast<const bf16x8*>(curA + rowA[m] + cx);
#pragma unroll
      for (int n = 0; n < 2; ++n) fb[n] = *reinterpret_cast<const bf16x8*>(curB + rowB[n] + cx);
    }
    BARRIER();
    asm volatile("s_waitcnt lgkmcnt(0)" ::: "memory");
    __builtin_amdgcn_sched_barrier(0);
    __builtin_amdgcn_s_setprio(1);
#pragma unroll
    for (int m = 0; m < 4; ++m)
#pragma unroll
      for (int n = 0; n < 2; ++n)
        acc[m][n] = __builtin_amdgcn_mfma_f32_16x16x32_bf16(fa[m], fb[n], acc[m][n], 0, 0, 0);
    __builtin_amdgcn_s_setprio(0);
    asm volatile("s_waitcnt vmcnt(0)" ::: "memory");
    BARRIER();
  }

#pragma unroll
  for (int m = 0; m < 4; ++m) {
    int r0 = mt * 128 + wr + m * 16 + ((lane >> 4) * 4);
#pragma unroll
    for (int j = 0; j < 4; ++j) {
      int r = r0 + j;
      if (r < cnt) {
        unsigned short* dst = yw + (size_t)(base + r) * HDIM + nt * 128 + wc + (lane & 15);
#pragma unroll
        for (int n = 0; n < 2; ++n) dst[n * 16] = f2bf(acc[m][n][j]);
      }
    }
  }
}

// ---------------- combine: out = x + w0*y0 + w1*y1 ----------------
__global__ __launch_bounds__(256) void k_combine(
    const float* __restrict__ x, const unsigned short* __restrict__ yw,
    const int* __restrict__ slotmap, const float* __restrict__ wl,
    float* __restrict__ out) {
  const int n = blockIdx.x;
  const int t = threadIdx.x;
  const int s0 = slotmap[2 * n], s1 = slotmap[2 * n + 1];
  const float w0 = wl[s0], w1 = wl[s1];
  float4 xv = reinterpret_cast<const float4*>(x + (size_t)n * HDIM)[t];
  ushort4 a0 = reinterpret_cast<const ushort4*>(yw + (size_t)s0 * HDIM)[t];
  ushort4 b0 = reinterpret_cast<const ushort4*>(yw + (size_t)s1 * HDIM)[t];
  float4 r;
  r.x = xv.x + w0 * bf2f(a0.x) + w1 * bf2f(b0.x);
  r.y = xv.y + w0 * bf2f(a0.y) + w1 * bf2f(b0.y);
  r.z = xv.z + w0 * bf2f(a0.z) + w1 * bf2f(b0.z);
  r.w = xv.w + w0 * bf2f(a0.w) + w1 * bf2f(b0.w);
  reinterpret_cast<float4*>(out + (size_t)n * HDIM)[t] = r;
}

extern "C" void kernel_launch(void* const* d_in, const int* in_sizes, int n_in,
                              void* d_out, int out_size, void* d_ws, size_t ws_size,
                              hipStream_t stream) {
  const float* x    = (const float*)d_in[0];
  const int* amask  = (const int*)d_in[1];
  const float* ew   = (const float*)d_in[2];
  const int* cidx   = (const int*)d_in[3];
  const float* dn   = (const float*)d_in[4];
  const float* up   = (const float*)d_in[5];
  float* out        = (float*)d_out;
  char* ws          = (char*)d_ws;

  const size_t X16_OFF = 0;
  const size_t DNT_OFF = X16_OFF + (size_t)NTOK * HDIM * 2;             // 8.4MB
  const size_t UPT_OFF = DNT_OFF + (size_t)NEXP * HDIM * DDIM * 2;      // +33.5MB
  const size_t HID_OFF = UPT_OFF + (size_t)NEXP * HDIM * DDIM * 2;      // +33.5MB
  const size_t MET_OFF = HID_OFF + (size_t)NASS * DDIM * 2;             // +33.5MB

  unsigned short* x16 = (unsigned short*)(ws + X16_OFF);
  unsigned short* dnT = (unsigned short*)(ws + DNT_OFF);
  unsigned short* upT = (unsigned short*)(ws + UPT_OFF);
  unsigned short* hid = (unsigned short*)(ws + HID_OFF);
  // yw ([NASS][HDIM] bf16, 16.8MB) aliases dnT: dnT dead after k_gemm_down
  unsigned short* yw  = (unsigned short*)(ws + DNT_OFF);
  int* counts  = (int*)(ws + MET_OFF);
  int* offs    = counts + 8;
  int* toks    = counts + 32;
  float* wl    = (float*)(toks + NASS);
  int* slotmap = (int*)(wl + NASS);

  k_cvt_x<<<NTOK * HDIM / 1024, 256, 0, stream>>>(x, x16);
  k_transpose<<<dim3(DDIM / 32, HDIM / 32, NEXP), 256, 0, stream>>>(dn, dnT, HDIM, DDIM);
  k_transpose<<<dim3(HDIM / 32, DDIM / 32, NEXP), 256, 0, stream>>>(up, upT, DDIM, HDIM);
  k_route<<<1, 1024, 0, stream>>>(cidx, ew, amask, counts, offs, toks, wl, slotmap);
  // blockIdx.x == XCD id (round-robin dispatch) == expert id
  k_gemm_down<<<dim3(8, 1024), 512, 0, stream>>>(x16, dnT, counts, offs, toks, hid);
  k_gemm_up<<<dim3(8, 512), 512, 0, stream>>>(hid, upT, counts, offs, yw);
  k_combine<<<NTOK, 256, 0, stream>>>(x, yw, slotmap, wl, out);
}